// Round 14
// baseline (2849.680 us; speedup 1.0000x reference)
//
#include <hip/hip_runtime.h>

typedef _Float16 half8 __attribute__((ext_vector_type(8)));
typedef float floatx4 __attribute__((ext_vector_type(4)));
typedef unsigned int uintx4 __attribute__((ext_vector_type(4)));

#define B_ 64
#define S_ 512
#define H_ 1024

// Per-WAVE arrival subslots in .bss (zero at load; untouched by ws poison).
// slotB[mb*256 + cb*4 + pw]: publisher wave pw of block (cb,mb) raises it
// after ITS payload rows (4pw..4pw+3) are LLC-acked. Monotonic: every subslot
// advances by exactly S_ per launch (e0+1 init, then e0+t+2, t=0..S_-2).
// Per-launch base e0 = own subslot read before any arrival.
__device__ unsigned slotB[4 * 256];

__device__ __forceinline__ float sigmoidf_(float x) { return 1.0f / (1.0f + __expf(-x)); }
__device__ __forceinline__ float tanhf_(float x) {
    return 1.0f - 2.0f / (__expf(2.0f * x) + 1.0f);   // saturates correctly via __expf
}

// 256 blocks x 256 threads (r11 structure, best measured). Block (cb=bid&63,
// mb=bid>>6) owns the 16x16 tile: batches [16mb,16mb+16) x cols [16cb,16cb+16),
// full K=1024; wave w = K-quarter; K-reduce in LDS (double-buffered part,
// ONE __syncthreads per step).
//
// r14 changes vs r11 (each removes measured critical-path pollution):
//  1. housekeeping (out store of step t-1, emb prefetch t+2) issued as asm
//     BETWEEN the payload burst and a counted s_waitcnt vmcnt(2): burst
//     (oldest 8) is guaranteed complete, housekeeping keeps flying through
//     compute (absorbed by the publish drain). r11 paid ~1us HBM-ack on the
//     first poll of EVERY step for these (implicit vmcnt(0) in the poll).
//  2. publish is barrier-free: wave pw drains its own payload store
//     (vmcnt(0), only its ops outstanding) and raises its OWN subslot.
//     Consumer wave w polls its 64 source subslots (publishers 16w..16w+16
//     x 4 waves = contiguous slotB[mb*256+w*64+lane]).
//  3. out = plain store (L2-ack, kernel-end writeback), not nontemporal.
// WAR safety (unchanged): block X writes xi buffer[(t+1)&1] only after its
// poll(t); poll(t) passing proves all 64 publishers (all waves) published
// step t, which (publish follows reduce-sync follows their poll(t-1)+reads)
// proves everyone finished reading buffer[(t-1)&1] == buffer[(t+1)&1].
__global__ void __launch_bounds__(256, 1)
lstm_scan(const float* __restrict__ emb, const float* __restrict__ W, const float* __restrict__ bW,
          const float* __restrict__ U, const float* __restrict__ bU,
          const float* __restrict__ V, const float* __restrict__ bV,
          float* __restrict__ out, unsigned char* __restrict__ ws)
{
    const int bid  = blockIdx.x;
    const int cb   = bid & 63;    // column group (16 H-cols)
    const int mb   = bid >> 6;    // batch group (16 batches)
    const int tid  = threadIdx.x;
    const int w    = tid >> 6;    // wave id = K-quarter AND publisher-wave id
    const int lane = tid & 63;
    const int fr   = lane & 15;   // A-frag row index
    const int kg   = lane >> 4;   // A-frag k-block

    char* pubc = (char*)ws;       // [2][64 rows][2048 B] packed f16 xi

    __shared__ __align__(16) float part[2][4 * 3 * 64 * 4];   // 2 x 12 KB

    const unsigned e0 = __hip_atomic_load(&slotB[mb * 256 + cb * 4 + w],
                                          __ATOMIC_RELAXED, __HIP_MEMORY_SCOPE_AGENT);

    // ---- persistent weight fragments (f16, registers): 3 gates x 8 ksteps ----
    // B-frag of mfma_f32_16x16x32_f16: lane l holds B[k=(l>>4)*8+e][n=l&15],
    // B[k][n] = Wgate[16*cb + n][k].  (Layout proven rounds 1/4-13.)
    half8 Bf[3][8];
    {
        const int jrow = cb * 16 + fr;
        const int kb   = w * 256 + kg * 8;
        const float* p0 = W + jrow * H_ + kb;
        const float* p1 = U + jrow * H_ + kb;
        const float* p2 = V + jrow * H_ + kb;
        #pragma unroll
        for (int ks = 0; ks < 8; ++ks) {
            half8 h0, h1, h2;
            #pragma unroll
            for (int e = 0; e < 8; ++e) {
                h0[e] = (_Float16)p0[ks * 32 + e];
                h1[e] = (_Float16)p1[ks * 32 + e];
                h2[e] = (_Float16)p2[ks * 32 + e];
            }
            Bf[0][ks] = h0; Bf[1][ks] = h1; Bf[2][ks] = h2;
        }
    }

    // ---- elementwise ownership: thread -> ONE cell (b, j); wave w owns rows 4w..4w+3 ----
    const int rt = tid >> 4;              // = 4w + (lane>>4)
    const int ct = tid & 15;
    const int b  = mb * 16 + rt;
    const int j  = cb * 16 + ct;
    const float bw = bW[j], bu = bU[j], bv = bV[j];
    const int rl = (rt >> 2) * 16 + ct;   // C/D source lane (proven)
    const int rr = rt & 3;                // C/D source reg
    const bool evenct = (ct & 1) == 0;
    // payload address (even-ct lanes store 4B = 2 packed f16)
    char* const paybase = pubc + (unsigned)(b * 2048 + cb * 32 + (ct >> 1) * 4);

    // publish own wave's rows: pack pairs, even-ct 4B sc1 store, drain OWN
    // stores only, raise OWN subslot. No cross-wave barrier.
    auto publish = [&](int buf, unsigned slotval, float xin) {
        union { _Float16 h; unsigned short u; } cvp; cvp.h = (_Float16)xin;
        unsigned mine  = cvp.u;
        unsigned other = (unsigned)__shfl_xor((int)mine, 1);
        unsigned pk = mine | (other << 16);
        if (evenct) {
            char* pa = paybase + buf * (64 * 2048);
            asm volatile("global_store_dword %0, %1, off sc0 sc1 nt"
                         :: "v"(pa), "v"(pk) : "memory");
        }
        asm volatile("s_waitcnt vmcnt(0)" ::: "memory");   // own payload acked at LLC
        __builtin_amdgcn_sched_barrier(0);
        if (lane == 0)
            __hip_atomic_store(&slotB[mb * 256 + cb * 4 + w], slotval,
                               __ATOMIC_RELAXED, __HIP_MEMORY_SCOPE_AGENT);
    };

    float p1s = 0.0f;
    float xio   = emb[(b * S_ + 0) * H_ + j];   // p2 init = 0
    float embA  = emb[(b * S_ + 1) * H_ + j];   // xi source for t+1
    float p2prev = 0.0f;
    publish(0, e0 + 1u, xio);

    for (int t = 0; t < S_; ++t) {
        // ---- poll: 64 source subslots (publishers 16w..16w+16 x 4 waves) ----
        {
            const unsigned tgt = e0 + (unsigned)t + 1u;
            const unsigned sidx = (unsigned)(mb * 256 + w * 64 + lane);
            for (;;) {
                unsigned v = __hip_atomic_load(&slotB[sidx], __ATOMIC_RELAXED,
                                               __HIP_MEMORY_SCOPE_AGENT);
                if (__all((int)(v - tgt) >= 0)) break;
                __builtin_amdgcn_s_sleep(1);
            }
            asm volatile("" ::: "memory");
        }

        // ---- payload burst: 8 forced dwordx4 sc1 (oldest; counted wait) ----
        const char* base = pubc + (unsigned)(((t & 1) * 64 + mb * 16 + fr) * 2048
                                             + w * 512 + kg * 16);
        uintx4 q0, q1, q2, q3, q4, q5, q6, q7;
        asm volatile("global_load_dwordx4 %0, %1, off sc1"            : "=v"(q0) : "v"(base));
        asm volatile("global_load_dwordx4 %0, %1, off offset:64 sc1"  : "=v"(q1) : "v"(base));
        asm volatile("global_load_dwordx4 %0, %1, off offset:128 sc1" : "=v"(q2) : "v"(base));
        asm volatile("global_load_dwordx4 %0, %1, off offset:192 sc1" : "=v"(q3) : "v"(base));
        asm volatile("global_load_dwordx4 %0, %1, off offset:256 sc1" : "=v"(q4) : "v"(base));
        asm volatile("global_load_dwordx4 %0, %1, off offset:320 sc1" : "=v"(q5) : "v"(base));
        asm volatile("global_load_dwordx4 %0, %1, off offset:384 sc1" : "=v"(q6) : "v"(base));
        asm volatile("global_load_dwordx4 %0, %1, off offset:448 sc1" : "=v"(q7) : "v"(base));

        // ---- housekeeping issued AFTER the burst (newest -> excluded from
        // the counted wait): out store of step t-1 (plain, L2-ack) + emb
        // prefetch of t+2. Uniform instruction count every iteration.
        {
            const int tso = (t == 0) ? (S_ - 1) : (t - 1);   // dummy at t=0,
            float* oa = out + (unsigned)((b * S_ + tso) * H_ + j);  // overwritten by final flush
            asm volatile("global_store_dword %0, %1, off" :: "v"(oa), "v"(p2prev) : "memory");
            const int tse = (t + 2 < S_) ? (t + 2) : 0;      // harmless re-read at tail
            const float* ea = emb + (unsigned)((b * S_ + tse) * H_ + j);
            float embB;
            asm volatile("global_load_dword %0, %1, off" : "=v"(embB) : "v"(ea));
            // burst(8) oldest retired when <=2 outstanding; embB/out keep flying
            asm volatile("s_waitcnt vmcnt(2)" ::: "memory");
            __builtin_amdgcn_sched_barrier(0);

            // ---- MFMA from captured registers ----
            floatx4 a0 = {0.f, 0.f, 0.f, 0.f};
            floatx4 a1 = {0.f, 0.f, 0.f, 0.f};
            floatx4 a2 = {0.f, 0.f, 0.f, 0.f};
            union { uintx4 v; half8 h; } cva;
            #define DO_KS(ks, Q)                                                          \
            {                                                                             \
                cva.v = Q; half8 Af = cva.h;                                              \
                a0 = __builtin_amdgcn_mfma_f32_16x16x32_f16(Af, Bf[0][ks], a0, 0, 0, 0);  \
                a1 = __builtin_amdgcn_mfma_f32_16x16x32_f16(Af, Bf[1][ks], a1, 0, 0, 0);  \
                a2 = __builtin_amdgcn_mfma_f32_16x16x32_f16(Af, Bf[2][ks], a2, 0, 0, 0);  \
            }
            DO_KS(0, q0) DO_KS(1, q1) DO_KS(2, q2) DO_KS(3, q3)
            DO_KS(4, q4) DO_KS(5, q5) DO_KS(6, q6) DO_KS(7, q7)
            #undef DO_KS

            // ---- K-reduction in LDS (double-buffered, one sync) ----
            float* pp = part[t & 1];
            *(floatx4*)&pp[((w * 3 + 0) * 64 + lane) * 4] = a0;
            *(floatx4*)&pp[((w * 3 + 1) * 64 + lane) * 4] = a1;
            *(floatx4*)&pp[((w * 3 + 2) * 64 + lane) * 4] = a2;
            __syncthreads();

            float pf = bw, pu = bu, pv = bv;
            #pragma unroll
            for (int wv = 0; wv < 4; ++wv) {
                pf += pp[((wv * 3 + 0) * 64 + rl) * 4 + rr];
                pu += pp[((wv * 3 + 1) * 64 + rl) * 4 + rr];
                pv += pp[((wv * 3 + 2) * 64 + rl) * 4 + rr];
            }

            // ---- gates + state update ----
            float fg = sigmoidf_(pf);
            float ig = sigmoidf_(pu);
            float gg = tanhf_(pv);
            p1s = fg * p1s + ig * gg;
            float p2 = sigmoidf_(xio) * tanhf_(p1s);

            if (t < S_ - 1) {
                float xin = embA + p2;
                xio = xin;
                publish((t + 1) & 1, e0 + (unsigned)t + 2u, xin);  // drains embB/out too
            }
            embA   = embB;   // safe: after publish's vmcnt(0)+sched_barrier
            p2prev = p2;
        }
    }

    // final flush: out[t = S-1] (also overwrites the t=0 dummy write's target)
    out[(b * S_ + (S_ - 1)) * H_ + j] = p2prev;
}

extern "C" void kernel_launch(void* const* d_in, const int* in_sizes, int n_in,
                              void* d_out, int out_size, void* d_ws, size_t ws_size,
                              hipStream_t stream)
{
    const float* emb = (const float*)d_in[0];
    const float* W   = (const float*)d_in[1];
    const float* bWv = (const float*)d_in[2];
    const float* U   = (const float*)d_in[3];
    const float* bUv = (const float*)d_in[4];
    const float* V   = (const float*)d_in[5];
    const float* bVv = (const float*)d_in[6];
    float* outp = (float*)d_out;
    unsigned char* ws = (unsigned char*)d_ws;
    (void)in_sizes; (void)n_in; (void)out_size; (void)ws_size;

    void* args[] = {(void*)&emb, (void*)&W, (void*)&bWv, (void*)&U, (void*)&bUv,
                    (void*)&V, (void*)&bVv, (void*)&outp, (void*)&ws};
    hipError_t err = hipLaunchCooperativeKernel((const void*)lstm_scan,
                                                dim3(256), dim3(256), args, 0, stream);
    if (err != hipSuccess) {
        lstm_scan<<<dim3(256), dim3(256), 0, stream>>>(emb, W, bWv, U, bUv, V, bVv, outp, ws);
    }
}

// Round 15
// 2644.613 us; speedup vs baseline: 1.0775x; 1.0775x over previous
//
#include <hip/hip_runtime.h>

typedef _Float16 half8 __attribute__((ext_vector_type(8)));
typedef float floatx4 __attribute__((ext_vector_type(4)));
typedef unsigned int uintx4 __attribute__((ext_vector_type(4)));
typedef unsigned long long u64t;

#define B_ 64
#define S_ 512
#define H_ 1024

// Arrival slots in .bss (zero at load; untouched by ws poison). Monotonic:
// each block's slot advances by exactly S_ per launch. Per-launch base e0 =
// own slot value read before any arrival (only the owner writes its slot;
// all slots equal at quiescence).  [r11-proven]
__device__ unsigned slotA[4][64];

__device__ __forceinline__ float sigmoidf_(float x) { return 1.0f / (1.0f + __expf(-x)); }
__device__ __forceinline__ float tanhf_(float x) {
    return 1.0f - 2.0f / (__expf(2.0f * x) + 1.0f);   // saturates correctly via __expf
}

// 256 blocks x 256 threads -- r11 structure and protocol VERBATIM (best
// measured: 2.22 ms). Block (cb=bid&63, mb=bid>>6) owns the 16x16 tile,
// full K=1024; wave w = K-quarter; K-reduce in double-buffered LDS, one
// __syncthreads per step; publish = packed 8B sc1 stores -> vmcnt(0) ->
// __syncthreads -> tid0 slot store; poll = wave polls its 16 source slots.
//
// r15 change (ONLY one): housekeeping is batched per OCTAVE of 8 steps so
// phases 1-6 have ZERO extra VMEM on the poll/publish critical path:
//  - emb prefetch: 8 loads issued at phase 0 right after the payload burst,
//    excluded from the burst wait by counted s_waitcnt vmcnt(8) (in-order
//    retirement: burst = oldest 8). They drain into phase 0's publish.
//  - out: buffered in 8 registers, flushed as 8 plain stores at phase 7.
// r11 paid ~1us of HBM-ack on EVERY step's first poll for these two ops.
__global__ void __launch_bounds__(256, 1)
lstm_scan(const float* __restrict__ emb, const float* __restrict__ W, const float* __restrict__ bW,
          const float* __restrict__ U, const float* __restrict__ bU,
          const float* __restrict__ V, const float* __restrict__ bV,
          float* __restrict__ out, unsigned char* __restrict__ ws)
{
    const int bid  = blockIdx.x;
    const int cb   = bid & 63;    // column group (16 H-cols)
    const int mb   = bid >> 6;    // batch group (16 batches)
    const int tid  = threadIdx.x;
    const int w    = tid >> 6;    // wave id = K-quarter
    const int lane = tid & 63;
    const int fr   = lane & 15;   // A-frag row index
    const int kg   = lane >> 4;   // A-frag k-block

    u64t* pub  = (u64t*)ws;       // [2][64 rows][256 words] 4 f16/word = 256 KB
    char* pubc = (char*)ws;

    __shared__ __align__(16) float part[2][4 * 3 * 64 * 4];   // 2 x 12 KB

    const unsigned e0 = __hip_atomic_load(&slotA[mb][cb], __ATOMIC_RELAXED,
                                          __HIP_MEMORY_SCOPE_AGENT);

    // ---- persistent weight fragments (f16, registers): 3 gates x 8 ksteps ----
    // B-frag of mfma_f32_16x16x32_f16: lane l holds B[k=(l>>4)*8+e][n=l&15],
    // B[k][n] = Wgate[16*cb + n][k].  (Layout proven rounds 1/4-14.)
    half8 Bf[3][8];
    {
        const int jrow = cb * 16 + fr;
        const int kb   = w * 256 + kg * 8;
        const float* p0 = W + jrow * H_ + kb;
        const float* p1 = U + jrow * H_ + kb;
        const float* p2 = V + jrow * H_ + kb;
        #pragma unroll
        for (int ks = 0; ks < 8; ++ks) {
            half8 h0, h1, h2;
            #pragma unroll
            for (int e = 0; e < 8; ++e) {
                h0[e] = (_Float16)p0[ks * 32 + e];
                h1[e] = (_Float16)p1[ks * 32 + e];
                h2[e] = (_Float16)p2[ks * 32 + e];
            }
            Bf[0][ks] = h0; Bf[1][ks] = h1; Bf[2][ks] = h2;
        }
    }

    // ---- elementwise ownership: thread -> ONE cell (b, j) ----
    const int rt = tid >> 4;
    const int ct = tid & 15;
    const int b  = mb * 16 + rt;
    const int j  = cb * 16 + ct;
    const float bw = bW[j], bu = bU[j], bv = bV[j];
    const int rl = (rt >> 2) * 16 + ct;   // C/D source lane (proven)
    const int rr = rt & 3;                // C/D source reg

    // publish (r11 verbatim): pack 4 f16 into one 8B sc1 word, drain, join
    // waves, tid0 raises the block slot.
    auto publish = [&](int buf, unsigned slotval, float xin) {
        union { _Float16 h; unsigned short u; } cvp; cvp.h = (_Float16)xin;
        unsigned mine = cvp.u;
        unsigned lo = mine | ((unsigned)__shfl_xor((int)mine, 1) << 16);
        unsigned hi = (unsigned)__shfl_xor((int)lo, 2);
        if ((ct & 3) == 0)
            __hip_atomic_store(&pub[(unsigned)(buf * 16384 + b * 256 + cb * 4 + (ct >> 2))],
                               (u64t)lo | ((u64t)hi << 32),
                               __ATOMIC_RELAXED, __HIP_MEMORY_SCOPE_AGENT);
        asm volatile("s_waitcnt vmcnt(0)" ::: "memory");  // payload acked at LLC
        __syncthreads();
        if (tid == 0)
            __hip_atomic_store(&slotA[mb][cb], slotval, __ATOMIC_RELAXED,
                               __HIP_MEMORY_SCOPE_AGENT);
    };

    // poll (r11 verbatim): wave w polls its 16 source publishers' slots.
    auto waitsrc = [&](unsigned tgt) {
        const int sidx = w * 16 + (lane & 15);
        for (;;) {
            unsigned v = __hip_atomic_load(&slotA[mb][sidx], __ATOMIC_RELAXED,
                                           __HIP_MEMORY_SCOPE_AGENT);
            if (__all((int)(v - tgt) >= 0)) break;
            __builtin_amdgcn_s_sleep(1);
        }
        asm volatile("" ::: "memory");
    };

    float p1s = 0.0f;
    float xio = emb[(b * S_ + 0) * H_ + j];    // p2 init = 0
    publish(0, e0 + 1u, xio);

    // octave emb buffers: invariant at octave start tb: embv[i] = emb[tb+1+i]
    float embv[8], embw[8], obuf[8];
    #pragma unroll
    for (int i = 0; i < 8; ++i)
        embv[i] = emb[(unsigned)((b * S_ + 1 + i) * H_ + j)];   // one-time

    for (int tb = 0; tb < S_; tb += 8) {
        #pragma unroll
        for (int tt = 0; tt < 8; ++tt) {
            const int t = tb + tt;
            waitsrc(e0 + (unsigned)t + 1u);

            // ---- payload burst: 8 forced dwordx4 sc1 (oldest in queue) ----
            const char* base = pubc + (unsigned)(((tt & 1) * 64 + mb * 16 + fr) * 2048
                                                 + w * 512 + kg * 16);
            uintx4 q0, q1, q2, q3, q4, q5, q6, q7;
            asm volatile("global_load_dwordx4 %0, %1, off sc1"            : "=v"(q0) : "v"(base));
            asm volatile("global_load_dwordx4 %0, %1, off offset:64 sc1"  : "=v"(q1) : "v"(base));
            asm volatile("global_load_dwordx4 %0, %1, off offset:128 sc1" : "=v"(q2) : "v"(base));
            asm volatile("global_load_dwordx4 %0, %1, off offset:192 sc1" : "=v"(q3) : "v"(base));
            asm volatile("global_load_dwordx4 %0, %1, off offset:256 sc1" : "=v"(q4) : "v"(base));
            asm volatile("global_load_dwordx4 %0, %1, off offset:320 sc1" : "=v"(q5) : "v"(base));
            asm volatile("global_load_dwordx4 %0, %1, off offset:384 sc1" : "=v"(q6) : "v"(base));
            asm volatile("global_load_dwordx4 %0, %1, off offset:448 sc1" : "=v"(q7) : "v"(base));

            if (tt == 0) {
                // octave emb prefetch for NEXT octave: embw[i] = emb[tb+9+i]
                // (clamped at the tail; clamped values are never consumed).
                #pragma unroll
                for (int i = 0; i < 8; ++i) {
                    int te = tb + 9 + i; if (te > S_ - 1) te = S_ - 1;
                    const float* ea = emb + (unsigned)((b * S_ + te) * H_ + j);
                    asm volatile("global_load_dword %0, %1, off" : "=v"(embw[i]) : "v"(ea));
                }
                // burst (oldest 8) done; emb prefetches (newest 8) keep flying
                asm volatile("s_waitcnt vmcnt(8)" ::: "memory");
            } else {
                asm volatile("s_waitcnt vmcnt(0)" ::: "memory");
            }
            __builtin_amdgcn_sched_barrier(0);

            // ---- MFMA from captured registers ----
            floatx4 a0 = {0.f, 0.f, 0.f, 0.f};
            floatx4 a1 = {0.f, 0.f, 0.f, 0.f};
            floatx4 a2 = {0.f, 0.f, 0.f, 0.f};
            union { uintx4 v; half8 h; } cva;
            #define DO_KS(ks, Q)                                                          \
            {                                                                             \
                cva.v = Q; half8 Af = cva.h;                                              \
                a0 = __builtin_amdgcn_mfma_f32_16x16x32_f16(Af, Bf[0][ks], a0, 0, 0, 0);  \
                a1 = __builtin_amdgcn_mfma_f32_16x16x32_f16(Af, Bf[1][ks], a1, 0, 0, 0);  \
                a2 = __builtin_amdgcn_mfma_f32_16x16x32_f16(Af, Bf[2][ks], a2, 0, 0, 0);  \
            }
            DO_KS(0, q0) DO_KS(1, q1) DO_KS(2, q2) DO_KS(3, q3)
            DO_KS(4, q4) DO_KS(5, q5) DO_KS(6, q6) DO_KS(7, q7)
            #undef DO_KS

            // ---- K-reduction in LDS (double-buffered, one sync) ----
            float* pp = part[tt & 1];
            *(floatx4*)&pp[((w * 3 + 0) * 64 + lane) * 4] = a0;
            *(floatx4*)&pp[((w * 3 + 1) * 64 + lane) * 4] = a1;
            *(floatx4*)&pp[((w * 3 + 2) * 64 + lane) * 4] = a2;
            __syncthreads();

            float pf = bw, pu = bu, pv = bv;
            #pragma unroll
            for (int wv = 0; wv < 4; ++wv) {
                pf += pp[((wv * 3 + 0) * 64 + rl) * 4 + rr];
                pu += pp[((wv * 3 + 1) * 64 + rl) * 4 + rr];
                pv += pp[((wv * 3 + 2) * 64 + rl) * 4 + rr];
            }

            // ---- gates + state update ----
            float fg = sigmoidf_(pf);
            float ig = sigmoidf_(pu);
            float gg = tanhf_(pv);
            p1s = fg * p1s + ig * gg;
            float p2 = sigmoidf_(xio) * tanhf_(p1s);
            obuf[tt] = p2;

            if (tt == 7) {
                // octave out flush: 8 plain stores (L2-ack), absorbed by this
                // phase's publish drain (or the final vmcnt below at t=S-1).
                #pragma unroll
                for (int i = 0; i < 8; ++i) {
                    float* oa = out + (unsigned)((b * S_ + tb + i) * H_ + j);
                    asm volatile("global_store_dword %0, %1, off" :: "v"(oa), "v"(obuf[i]) : "memory");
                }
            }

            if (t < S_ - 1) {
                float xin = embv[tt] + p2;
                xio = xin;
                publish((tt + 1) & 1, e0 + (unsigned)t + 2u, xin);
            }

            if (tt == 7) {
                // rotate octave emb buffer (prefetches guaranteed landed by
                // phase 0's publish vmcnt(0))
                #pragma unroll
                for (int i = 0; i < 8; ++i) embv[i] = embw[i];
            }
        }
    }

    // drain the final octave's out flush before endpgm
    asm volatile("s_waitcnt vmcnt(0)" ::: "memory");
}

extern "C" void kernel_launch(void* const* d_in, const int* in_sizes, int n_in,
                              void* d_out, int out_size, void* d_ws, size_t ws_size,
                              hipStream_t stream)
{
    const float* emb = (const float*)d_in[0];
    const float* W   = (const float*)d_in[1];
    const float* bWv = (const float*)d_in[2];
    const float* U   = (const float*)d_in[3];
    const float* bUv = (const float*)d_in[4];
    const float* V   = (const float*)d_in[5];
    const float* bVv = (const float*)d_in[6];
    float* outp = (float*)d_out;
    unsigned char* ws = (unsigned char*)d_ws;
    (void)in_sizes; (void)n_in; (void)out_size; (void)ws_size;

    void* args[] = {(void*)&emb, (void*)&W, (void*)&bWv, (void*)&U, (void*)&bUv,
                    (void*)&V, (void*)&bVv, (void*)&outp, (void*)&ws};
    hipError_t err = hipLaunchCooperativeKernel((const void*)lstm_scan,
                                                dim3(256), dim3(256), args, 0, stream);
    if (err != hipSuccess) {
        lstm_scan<<<dim3(256), dim3(256), 0, stream>>>(emb, W, bWv, U, bUv, V, bVv, outp, ws);
    }
}